// Round 13
// baseline (385.571 us; speedup 1.0000x reference)
//
#include <hip/hip_runtime.h>
#include <hip/hip_bf16.h>

// ---------------------------------------------------------------------------
// KascadeReuseAttention: B=2,S=4096,H=16,D=128, TILE=128, T=32, TOPK=7(+local)
// R13: gemm256 -> faithful m201 8-phase skeleton: K-half panels [256][32] in
// 4-slot rings (128KiB), per phase {ds_reads+1 half-panel stage | barrier |
// lgkmcnt(0) | 16 MFMA | barrier}, vmcnt(4) once per K-tile (never 0 in
// loop). Wave tiling 4Mx2N kept -> fused rope/V^T epilogue unchanged.
// attn = R9/R12 version. wtrans4 + M-fastest block map kept.
// ---------------------------------------------------------------------------

typedef __bf16 bf16_t;
using bf16x8 = __attribute__((ext_vector_type(8))) __bf16;
using bf16x4 = __attribute__((ext_vector_type(4))) __bf16;
using f32x4  = __attribute__((ext_vector_type(4))) float;

typedef const __attribute__((address_space(1))) void* gas_ptr;
typedef __attribute__((address_space(3))) void* las_ptr;

__device__ __forceinline__ void async_copy16(const void* g, void* l) {
  __builtin_amdgcn_global_load_lds((gas_ptr)g, (las_ptr)l, 16, 0, 0);
}

__device__ __forceinline__ f32x4 mfma16x16x32(bf16x8 a, bf16x8 b, f32x4 c) {
  return __builtin_amdgcn_mfma_f32_16x16x32_bf16(a, b, c, 0, 0, 0);
}

#define SBAR0() __builtin_amdgcn_sched_barrier(0)

// ---------------- elementwise f32 -> bf16 (vectorized) ----------------------
__global__ void cvt_f32_bf16(const float* __restrict__ X, bf16_t* __restrict__ Y) {
  int idx = blockIdx.x * 256 + threadIdx.x;
  float4 v = ((const float4*)X)[idx];
  bf16x4 r;
  r.x = (bf16_t)v.x; r.y = (bf16_t)v.y; r.z = (bf16_t)v.z; r.w = (bf16_t)v.w;
  ((bf16x4*)Y)[idx] = r;
}

// -------- weight transpose+convert x4 in one launch: W f32 -> Wt bf16 -------
__global__ void wtrans4(const float* __restrict__ wq, const float* __restrict__ wk,
                        const float* __restrict__ wv, const float* __restrict__ wo,
                        bf16_t* __restrict__ wcat, bf16_t* __restrict__ wot) {
  __shared__ bf16_t t[64][66];
  const int z = blockIdx.z;
  const float* W = (z == 0) ? wq : (z == 1) ? wk : (z == 2) ? wv : wo;
  bf16_t* Wt = (z == 3) ? wot : (wcat + (size_t)z * 2048 * 2048);
  const int r0 = blockIdx.x * 64, c0 = blockIdx.y * 64;
  const int tx = threadIdx.x & 63, ty = threadIdx.x >> 6;
  #pragma unroll
  for (int i = 0; i < 16; ++i) {
    int r = ty + 4 * i;
    t[r][tx] = (bf16_t)W[(size_t)(r0 + r) * 2048 + c0 + tx];
  }
  __syncthreads();
  #pragma unroll
  for (int i = 0; i < 16; ++i) {
    int n = ty + 4 * i;
    Wt[(size_t)(c0 + n) * 2048 + r0 + tx] = t[tx][n];
  }
}

// ---------------- GEMM 256x256, m201 8-phase: C[8192][Ntot] = A * Bt^T ------
// 8 waves as 4M x 2N (per-wave 64Mx128N; head span in-thread for rope).
// LDS: per matrix a 4-slot ring of K-HALF panels [256 rows][32 k] bf16
// (16KB/slot; A 64KB + B 64KB = 128KiB). Half H = 2*tile + kc, slot = H&3.
// Swizzle: rows of 4x16B chunks, ch ^= (row>>1)&3 (write-source + read).
// Tile t = 4 phases; phase = {frag ds_reads | stage 1 half-panel | barrier |
// lgkmcnt(0) | setprio(1) 16 MFMA setprio(0) | barrier}. Stage stream:
// ph0 A(2t+3), ph1 B(2t+3), ph2 A(2t+4), ph3 B(2t+4). vmcnt(4) at ph3 only
// (keeps {A,B}(2t+4) in flight; retires tile t+1's halves). WAR: each staged
// slot's last reader finished >=1 barrier-pair before the stage issues.
// Tail: t=30 stages only (A,B)63 then vmcnt(0); t=31 stages nothing.
// mode 0: f32 C row-major (nb=8). mode 1: fused QKV (nb=24).
__global__ __launch_bounds__(512, 2) void gemm256(
    const bf16_t* __restrict__ A, const bf16_t* __restrict__ Bt,
    int nb, int mode, float* __restrict__ Cf,
    bf16_t* __restrict__ outQ, bf16_t* __restrict__ outK,
    bf16_t* __restrict__ outVT,
    const float* __restrict__ cosT, const float* __restrict__ sinT)
{
  __shared__ bf16_t Apan[4][8192];   // 4 half-slots x [256][32] = 16KB each
  __shared__ bf16_t Bpan[4][8192];
  const int bid = blockIdx.x;
  const int cpx = gridDim.x >> 3;
  const int swz = (bid & 7) * cpx + (bid >> 3);   // XCD-chunked (grid%8==0)
  const int RM = cpx / nb;                        // M-rows per chunk
  const int bm = ((swz / cpx) * RM + (swz % RM)) * 256;   // M fastest in chunk
  const int bn = ((swz % cpx) / RM) * 256;
  const int tid = threadIdx.x;
  const int w = tid >> 6, l = tid & 63;
  const int wr = w >> 1, wc = w & 1;              // 4M x 2N
  const int fr = l & 15, g4 = l >> 4;

  // staging: thread owns chunks c0=tid, c1=tid+512 of each [256][32] panel
  const int c0 = tid, c1 = tid + 512;
  const int r0 = c0 >> 2, ch0 = c0 & 3;
  const int r1 = c1 >> 2, ch1 = c1 & 3;
  const bf16_t* aS0 = A  + (size_t)(bm + r0) * 2048 + (ch0 ^ ((r0 >> 1) & 3)) * 8;
  const bf16_t* aS1 = A  + (size_t)(bm + r1) * 2048 + (ch1 ^ ((r1 >> 1) & 3)) * 8;
  const bf16_t* bS0 = Bt + (size_t)(bn + r0) * 2048 + (ch0 ^ ((r0 >> 1) & 3)) * 8;
  const bf16_t* bS1 = Bt + (size_t)(bn + r1) * 2048 + (ch1 ^ ((r1 >> 1) & 3)) * 8;
  const int d0 = c0 * 16, d1 = c1 * 16;

  // frag-read byte offsets within a [256][32] half-panel (row = 64B, 4 ch)
  int aOff[4], bOff[8];
  #pragma unroll
  for (int m = 0; m < 4; ++m) {
    int R = wr * 64 + m * 16 + fr;
    aOff[m] = R * 64 + ((g4 ^ ((R >> 1) & 3)) << 4);
  }
  #pragma unroll
  for (int n = 0; n < 8; ++n) {
    int R = wc * 128 + n * 16 + fr;
    bOff[n] = R * 64 + ((g4 ^ ((R >> 1) & 3)) << 4);
  }

  f32x4 acc[4][8];
  #pragma unroll
  for (int m = 0; m < 4; ++m)
    #pragma unroll
    for (int n = 0; n < 8; ++n) acc[m][n] = (f32x4){0.f, 0.f, 0.f, 0.f};

  auto STAGE_A = [&](int H) {      // stage A K-half H into slot H&3
    const int slot = H & 3;
    const int kb = (H >> 1) * 64 + (H & 1) * 32;
    char* dA = (char*)&Apan[slot][0];
    async_copy16(aS0 + kb, dA + d0);
    async_copy16(aS1 + kb, dA + d1);
  };
  auto STAGE_B = [&](int H) {
    const int slot = H & 3;
    const int kb = (H >> 1) * 64 + (H & 1) * 32;
    char* dB = (char*)&Bpan[slot][0];
    async_copy16(bS0 + kb, dB + d0);
    async_copy16(bS1 + kb, dB + d1);
  };

  // prologue: halves 0,1,2 staged; vmcnt(4) -> halves 0,1 (tile 0) landed
  STAGE_A(0); STAGE_B(0); STAGE_A(1); STAGE_B(1); STAGE_A(2); STAGE_B(2);
  asm volatile("s_waitcnt vmcnt(4)" ::: "memory");
  SBAR0();
  __builtin_amdgcn_s_barrier();
  SBAR0();

  #pragma unroll 1
  for (int t = 0; t < 32; ++t) {
    const char* pa0 = (const char*)&Apan[(2 * t) & 3][0];
    const char* pb0 = (const char*)&Bpan[(2 * t) & 3][0];
    const char* pa1 = (const char*)&Apan[(2 * t + 1) & 3][0];
    const char* pb1 = (const char*)&Bpan[(2 * t + 1) & 3][0];
    bf16x8 bq[8], a0, a1;

    // ---- phase 0: A m{0,1} kc0 + B all-n kc0 | stage A(2t+3) ----
    a0 = *(const bf16x8*)(pa0 + aOff[0]);
    a1 = *(const bf16x8*)(pa0 + aOff[1]);
    #pragma unroll
    for (int n = 0; n < 8; ++n) bq[n] = *(const bf16x8*)(pb0 + bOff[n]);
    if (t < 31) STAGE_A(2 * t + 3);
    SBAR0(); __builtin_amdgcn_s_barrier();
    asm volatile("s_waitcnt lgkmcnt(0)" ::: "memory");
    SBAR0();
    __builtin_amdgcn_s_setprio(1);
    #pragma unroll
    for (int n = 0; n < 8; ++n) {
      acc[0][n] = mfma16x16x32(a0, bq[n], acc[0][n]);
      acc[1][n] = mfma16x16x32(a1, bq[n], acc[1][n]);
    }
    __builtin_amdgcn_s_setprio(0);
    SBAR0(); __builtin_amdgcn_s_barrier(); SBAR0();

    // ---- phase 1: A m{2,3} kc0 (B kc0 reused) | stage B(2t+3) ----
    a0 = *(const bf16x8*)(pa0 + aOff[2]);
    a1 = *(const bf16x8*)(pa0 + aOff[3]);
    if (t < 31) STAGE_B(2 * t + 3);
    SBAR0(); __builtin_amdgcn_s_barrier();
    asm volatile("s_waitcnt lgkmcnt(0)" ::: "memory");
    SBAR0();
    __builtin_amdgcn_s_setprio(1);
    #pragma unroll
    for (int n = 0; n < 8; ++n) {
      acc[2][n] = mfma16x16x32(a0, bq[n], acc[2][n]);
      acc[3][n] = mfma16x16x32(a1, bq[n], acc[3][n]);
    }
    __builtin_amdgcn_s_setprio(0);
    SBAR0(); __builtin_amdgcn_s_barrier(); SBAR0();

    // ---- phase 2: A m{0,1} kc1 + B all-n kc1 | stage A(2t+4) ----
    a0 = *(const bf16x8*)(pa1 + aOff[0]);
    a1 = *(const bf16x8*)(pa1 + aOff[1]);
    #pragma unroll
    for (int n = 0; n < 8; ++n) bq[n] = *(const bf16x8*)(pb1 + bOff[n]);
    if (t < 30) STAGE_A(2 * t + 4);
    SBAR0(); __builtin_amdgcn_s_barrier();
    asm volatile("s_waitcnt lgkmcnt(0)" ::: "memory");
    SBAR0();
    __builtin_amdgcn_s_setprio(1);
    #pragma unroll
    for (int n = 0; n < 8; ++n) {
      acc[0][n] = mfma16x16x32(a0, bq[n], acc[0][n]);
      acc[1][n] = mfma16x16x32(a1, bq[n], acc[1][n]);
    }
    __builtin_amdgcn_s_setprio(0);
    SBAR0(); __builtin_amdgcn_s_barrier(); SBAR0();

    // ---- phase 3: A m{2,3} kc1 | stage B(2t+4) | tile-end vmcnt ----
    a0 = *(const bf16x8*)(pa1 + aOff[2]);
    a1 = *(const bf16x8*)(pa1 + aOff[3]);
    if (t < 30) STAGE_B(2 * t + 4);
    SBAR0(); __builtin_amdgcn_s_barrier();
    asm volatile("s_waitcnt lgkmcnt(0)" ::: "memory");
    SBAR0();
    __builtin_amdgcn_s_setprio(1);
    #pragma unroll
    for (int n = 0; n < 8; ++n) {
      acc[2][n] = mfma16x16x32(a0, bq[n], acc[2][n]);
      acc[3][n] = mfma16x16x32(a1, bq[n], acc[3][n]);
    }
    __builtin_amdgcn_s_setprio(0);
    if (t < 30)       asm volatile("s_waitcnt vmcnt(4)" ::: "memory");
    else if (t == 30) asm volatile("s_waitcnt vmcnt(0)" ::: "memory");
    SBAR0(); __builtin_amdgcn_s_barrier(); SBAR0();
  }

  if (mode == 0) {
    #pragma unroll
    for (int m = 0; m < 4; ++m)
      #pragma unroll
      for (int n = 0; n < 8; ++n)
        #pragma unroll
        for (int j = 0; j < 4; ++j) {
          int row = bm + wr * 64 + m * 16 + g4 * 4 + j;
          int col = bn + wc * 128 + n * 16 + fr;
          Cf[(size_t)row * 2048 + col] = acc[m][n][j];
        }
    return;
  }

  // ---- fused QKV epilogue ----
  const int colbase = bn + wc * 128;          // wave-uniform, multiple of 128
  const int proj = colbase >> 11;             // 0=Q 1=K 2=V
  const int hh = (colbase & 2047) >> 7;
  if (proj == 2) {
    #pragma unroll
    for (int m = 0; m < 4; ++m) {
      int row0 = bm + wr * 64 + m * 16 + g4 * 4;
      int b_ = row0 >> 12, sr = row0 & 4095;
      #pragma unroll
      for (int n = 0; n < 8; ++n) {
        int d_ = n * 16 + fr;
        bf16x4 pkv;
        #pragma unroll
        for (int j = 0; j < 4; ++j) pkv[j] = (bf16_t)acc[m][n][j];
        *(bf16x4*)&outVT[(((size_t)(b_ * 16 + hh)) * 128 + d_) * 4096 + sr] = pkv;
      }
    }
  } else {
    bf16_t* dst_ = proj ? outK : outQ;
    #pragma unroll
    for (int m = 0; m < 4; ++m) {
      int row0 = bm + wr * 64 + m * 16 + g4 * 4;
      int b_ = row0 >> 12, s0 = row0 & 4095;
      size_t hbase = ((size_t)(b_ * 16 + hh)) * 4096;
      #pragma unroll
      for (int n = 0; n < 4; ++n) {
        int d = n * 16 + fr;
        #pragma unroll
        for (int j = 0; j < 4; ++j) {
          int s = s0 + j;
          float c  = cosT[s * 64 + d];
          float sn = sinT[s * 64 + d];
          float x0 = acc[m][n][j], x1 = acc[m][n + 4][j];
          dst_[(hbase + s) * 128 + d]      = (bf16_t)(x0 * c - x1 * sn);
          dst_[(hbase + s) * 128 + d + 64] = (bf16_t)(x1 * c + x0 * sn);
        }
      }
    }
  }
}

// ---------------- sparse flash attention (R9/R12 version: KVBLK=64) ---------
__global__ __launch_bounds__(512, 4) void attn_kernel(
    const bf16_t* __restrict__ Qf, const bf16_t* __restrict__ Kf,
    const bf16_t* __restrict__ Vt, const int* __restrict__ anchors,
    bf16_t* __restrict__ outB)   // [B,S,2048] bf16
{
  __shared__ bf16_t Kl[2][8192];    // [64 tok][128 d] swizzled, 16KB each
  __shared__ bf16_t Vl[2][8192];    // [128 d][64 tok] swizzled, 16KB each
  __shared__ bf16_t Pbuf[8][1024];  // per-wave 2KB  (total LDS = 80KB exact)
  const int orig = blockIdx.x;
  const int blk = (orig & 7) * 128 + (orig >> 3);   // XCD-chunked swizzle
  const int qt = 31 - (blk & 31);                   // long blocks first
  const int h = (blk >> 5) & 15, b = blk >> 9;
  const int bh = b * 16 + h;
  const int tid = threadIdx.x, w = tid >> 6, l = tid & 63;
  const int fr = l & 15, g4 = l >> 4;
  const float scale = 0.08838834764831845f;   // 1/sqrt(128)

  const int* anc = anchors + ((size_t)bh * 32 + qt) * 7;
  unsigned long long pk = 0;
  int nt = 0;
  #pragma unroll
  for (int t = 0; t < 7; ++t) {
    int v = anc[t];
    if (v <= qt) { pk |= (unsigned long long)v << (5 * nt); ++nt; }
  }
  pk |= (unsigned long long)qt << (5 * nt); ++nt;   // local tile last
  const int NS = nt * 2;

  const bf16_t* Qbase = Qf + (size_t)bh * 4096 * 128;
  const bf16_t* Kbase = Kf + (size_t)bh * 4096 * 128;
  const bf16_t* Vbase = Vt + (size_t)bh * 128 * 4096;
  char* P = (char*)&Pbuf[w][0];

  auto STAGE = [&](int tb2, int p) {
    const bf16_t* ksrc = Kbase + (size_t)tb2 * 128;
    const bf16_t* vsrc = Vbase + tb2;
    char* kd = (char*)&Kl[p][0];
    char* vd = (char*)&Vl[p][0];
    #pragma unroll
    for (int i = 0; i < 2; ++i) {
      int c = tid + i * 512;                 // 0..1023
      int kr = c >> 4, kcol = c & 15;        // K: 64 rows x 16 chunks
      async_copy16(ksrc + (size_t)kr * 128 + (size_t)((kcol ^ (kr & 7)) * 8),
                   kd + c * 16);
      int vr = c >> 3, vcol = c & 7;         // V^T: 128 rows x 8 chunks
      async_copy16(vsrc + (size_t)vr * 4096 + (size_t)((vcol ^ (vr & 7)) * 8),
                   vd + c * 16);
    }
  };

  const int qrow = qt * 128 + w * 16 + fr;
  bf16x8 aq[4];
  #pragma unroll
  for (int kc = 0; kc < 4; ++kc)
    aq[kc] = *(const bf16x8*)(Qbase + (size_t)qrow * 128 + kc * 32 + g4 * 8);

  STAGE((int)(pk & 31) * 128, 0);
  __syncthreads();   // step-0 buffers landed

  float mrun = -1e30f, lrun = 0.f;
  f32x4 o[8];
  #pragma unroll
  for (int nd = 0; nd < 8; ++nd) o[nd] = (f32x4){0.f, 0.f, 0.f, 0.f};

  for (int s = 0; s < NS; ++s) {
    const int p = s & 1;
    const int ts = (int)((pk >> (5 * (s >> 1))) & 31);
    const bool domask = (ts == qt);
    if (s + 1 < NS) {
      int s1 = s + 1;
      int ts1 = (int)((pk >> (5 * (s1 >> 1))) & 31);
      STAGE(ts1 * 128 + (s1 & 1) * 64, p ^ 1);
    }

    f32x4 sc[4];
    #pragma unroll
    for (int n = 0; n < 4; ++n) sc[n] = (f32x4){0.f, 0.f, 0.f, 0.f};
    #pragma unroll
    for (int kc = 0; kc < 4; ++kc) {
      bf16x8 kf[4];
      #pragma unroll
      for (int n = 0; n < 4; ++n) {
        int r = n * 16 + fr;
        kf[n] = *(const bf16x8*)((const char*)&Kl[p][0] +
                 r * 256 + (((kc * 4 + g4) ^ (r & 7)) << 4));
      }
      #pragma unroll
      for (int n = 0; n < 4; ++n)
        sc[n] = mfma16x16x32(kf[n], aq[kc], sc[n]);
    }

    float rmax = -1e30f;
    if (domask) {
      const int qr = w * 16 + fr;
      #pragma unroll
      for (int n = 0; n < 4; ++n)
        #pragma unroll
        for (int j = 0; j < 4; ++j) {
          float lg = sc[n][j] * scale;
          int tok = (s & 1) * 64 + n * 16 + g4 * 4 + j;
          if (tok > qr) lg = -1e10f;
          sc[n][j] = lg;
          rmax = fmaxf(rmax, lg);
        }
    } else {
      #pragma unroll
      for (int n = 0; n < 4; ++n)
        #pragma unroll
        for (int j = 0; j < 4; ++j) {
          float lg = sc[n][j] * scale;
          sc[n][j] = lg;
          rmax = fmaxf(rmax, lg);
        }
    }
    rmax = fmaxf(rmax, __shfl_xor(rmax, 16));
    rmax = fmaxf(rmax, __shfl_xor(rmax, 32));
    if (__any(rmax > mrun + 8.f)) {          // defer-max (T13)
      float mnew = fmaxf(mrun, rmax);
      float alpha = __expf(mrun - mnew);
      lrun *= alpha;
      #pragma unroll
      for (int nd = 0; nd < 8; ++nd)
        #pragma unroll
        for (int j = 0; j < 4; ++j) o[nd][j] *= alpha;
      mrun = mnew;
    }
    float rsum = 0.f;
    #pragma unroll
    for (int n = 0; n < 4; ++n) {
      bf16x4 pkv;
      #pragma unroll
      for (int j = 0; j < 4; ++j) {
        float pe = __expf(sc[n][j] - mrun);
        rsum += pe;
        pkv[j] = (bf16_t)pe;
      }
      int off = fr * 128 + ((((n << 1) | (g4 >> 1)) ^ (fr & 7)) << 4) + ((g4 & 1) << 3);
      *(bf16x4*)(P + off) = pkv;
    }
    rsum += __shfl_xor(rsum, 16);
    rsum += __shfl_xor(rsum, 32);
    lrun += rsum;

    #pragma unroll
    for (int kc2 = 0; kc2 < 2; ++kc2) {
      bf16x8 av[8];
      #pragma unroll
      for (int nd = 0; nd < 8; ++nd) {
        int r = nd * 16 + fr;
        av[nd] = *(const bf16x8*)((const char*)&Vl[p][0] +
                  r * 128 + (((kc2 * 4 + g4) ^ (r & 7)) << 4));
      }
      bf16x8 bp = *(const bf16x8*)(P + fr * 128 + ((((kc2 << 2) | g4) ^ (fr & 7)) << 4));
      #pragma unroll
      for (int nd = 0; nd < 8; ++nd)
        o[nd] = mfma16x16x32(av[nd], bp, o[nd]);
    }
    __syncthreads();
  }

  {
    char* E = (char*)&Kl[0][0] + w * 4096;   // 16 rows x 256B per wave
    float inv = 1.0f / lrun;
    #pragma unroll
    for (int nd = 0; nd < 8; ++nd) {
      bf16x4 pkv;
      #pragma unroll
      for (int j = 0; j < 4; ++j) pkv[j] = (bf16_t)(o[nd][j] * inv);
      int off = fr * 256 + ((((nd << 1) | (g4 >> 1)) ^ (fr & 7)) << 4) + ((g4 & 1) << 3);
      *(bf16x4*)(E + off) = pkv;
    }
    #pragma unroll
    for (int i = 0; i < 4; ++i) {
      int r = i * 4 + g4;
      int off = r * 256 + ((fr ^ (r & 7)) << 4);
      bf16x8 vrow = *(const bf16x8*)(E + off);
      size_t gaddr = (((size_t)b * 4096 + qt * 128 + w * 16 + r) * 2048)
                     + h * 128 + fr * 8;
      *(bf16x8*)(outB + gaddr) = vrow;
    }
  }
}

// ---------------------------------------------------------------------------
// workspace layout (bytes)
#define OFF_XB   ((size_t)0)            // x bf16            [8192][2048]  32MB
#define OFF_WCAT ((size_t)33554432)     // concat wq^T|wk^T|wv^T bf16 [6144][2048] 24MB
#define OFF_WOT  ((size_t)58720256)     // wo^T bf16 [2048][2048] 8MB
#define OFF_QF   ((size_t)67108864)     // Q bf16 [B,H,S,D]  32MB
#define OFF_KF   ((size_t)100663296)    // K bf16 [B,H,S,D]  32MB
#define OFF_AT   ((size_t)134217728)    // attn out [B,S,2048] bf16 32MB
#define OFF_VT   ((size_t)167772160)    // V^T bf16 [B,H,D,S] 32MB

extern "C" void kernel_launch(void* const* d_in, const int* in_sizes, int n_in,
                              void* d_out, int out_size, void* d_ws, size_t ws_size,
                              hipStream_t stream) {
  (void)in_sizes; (void)n_in; (void)out_size; (void)ws_size;
  const float* x    = (const float*)d_in[0];
  const float* wq   = (const float*)d_in[1];
  const float* wk   = (const float*)d_in[2];
  const float* wv   = (const float*)d_in[3];
  const float* wo   = (const float*)d_in[4];
  const float* cosT = (const float*)d_in[5];
  const float* sinT = (const float*)d_in[6];
  const int*   anc  = (const int*)d_in[7];
  float* out = (float*)d_out;
  char* ws = (char*)d_ws;

  bf16_t* xb   = (bf16_t*)(ws + OFF_XB);
  bf16_t* wcat = (bf16_t*)(ws + OFF_WCAT);
  bf16_t* wot  = (bf16_t*)(ws + OFF_WOT);
  bf16_t* Qf   = (bf16_t*)(ws + OFF_QF);
  bf16_t* Kf   = (bf16_t*)(ws + OFF_KF);
  bf16_t* Vt   = (bf16_t*)(ws + OFF_VT);
  bf16_t* attnB = (bf16_t*)(ws + OFF_AT);

  cvt_f32_bf16<<<16384, 256, 0, stream>>>(x, xb);
  wtrans4<<<dim3(32, 32, 4), 256, 0, stream>>>(wq, wk, wv, wo, wcat, wot);
  // fused QKV projection + RoPE + V^T (grid 768 = 32 M-blocks x 24 N-blocks)
  gemm256<<<768, 512, 0, stream>>>(xb, wcat, 24, 1, nullptr, Qf, Kf, Vt, cosT, sinT);
  attn_kernel<<<1024, 512, 0, stream>>>(Qf, Kf, Vt, anc, attnB);
  // output projection (grid 256 = 32 x 8)
  gemm256<<<256, 512, 0, stream>>>(attnB, wot, 8, 0, out, nullptr, nullptr, nullptr,
                                   nullptr, nullptr);
}

// Round 14
// 351.948 us; speedup vs baseline: 1.0955x; 1.0955x over previous
//
#include <hip/hip_runtime.h>
#include <hip/hip_bf16.h>

// ---------------------------------------------------------------------------
// KascadeReuseAttention: B=2,S=4096,H=16,D=128, TILE=128, T=32, TOPK=7(+local)
// R14: consolidation. GEMM loop = R12 (best measured: BK=64, 2-slot,
// 1 barrier/phase, M-fastest chunk map). NEW: (1) mode-0 epilogue stores
// coalesced via per-wave LDS scratch (full 512B row segments); (2) cvt +
// wtrans merged into one prep dispatch. attn = R9/R12 version.
// ---------------------------------------------------------------------------

typedef __bf16 bf16_t;
using bf16x8 = __attribute__((ext_vector_type(8))) __bf16;
using bf16x4 = __attribute__((ext_vector_type(4))) __bf16;
using f32x4  = __attribute__((ext_vector_type(4))) float;

typedef const __attribute__((address_space(1))) void* gas_ptr;
typedef __attribute__((address_space(3))) void* las_ptr;

__device__ __forceinline__ void async_copy16(const void* g, void* l) {
  __builtin_amdgcn_global_load_lds((gas_ptr)g, (las_ptr)l, 16, 0, 0);
}

__device__ __forceinline__ f32x4 mfma16x16x32(bf16x8 a, bf16x8 b, f32x4 c) {
  return __builtin_amdgcn_mfma_f32_16x16x32_bf16(a, b, c, 0, 0, 0);
}

// -------- prep: weight transpose x4 + x f32->bf16, one dispatch -------------
// blocks 0..4095: wtrans tiles (z = b>>10, tile = b&1023 -> 32x32 of 64x64).
// blocks 4096..20479: cvt chunks (1024 f32 each).
__global__ void prep_kernel(const float* __restrict__ x, const float* __restrict__ wq,
                            const float* __restrict__ wk, const float* __restrict__ wv,
                            const float* __restrict__ wo, bf16_t* __restrict__ xb,
                            bf16_t* __restrict__ wcat, bf16_t* __restrict__ wot) {
  __shared__ bf16_t t[64][66];
  const int bidx = blockIdx.x;
  if (bidx >= 4096) {
    int idx = (bidx - 4096) * 256 + threadIdx.x;
    float4 v = ((const float4*)x)[idx];
    bf16x4 r;
    r.x = (bf16_t)v.x; r.y = (bf16_t)v.y; r.z = (bf16_t)v.z; r.w = (bf16_t)v.w;
    ((bf16x4*)xb)[idx] = r;
    return;
  }
  const int z = bidx >> 10, bt = bidx & 1023;
  const float* W = (z == 0) ? wq : (z == 1) ? wk : (z == 2) ? wv : wo;
  bf16_t* Wt = (z == 3) ? wot : (wcat + (size_t)z * 2048 * 2048);
  const int r0 = (bt >> 5) * 64, c0 = (bt & 31) * 64;
  const int tx = threadIdx.x & 63, ty = threadIdx.x >> 6;
  #pragma unroll
  for (int i = 0; i < 16; ++i) {
    int r = ty + 4 * i;
    t[r][tx] = (bf16_t)W[(size_t)(r0 + r) * 2048 + c0 + tx];
  }
  __syncthreads();
  #pragma unroll
  for (int i = 0; i < 16; ++i) {
    int n = ty + 4 * i;
    Wt[(size_t)(c0 + n) * 2048 + r0 + tx] = t[tx][n];
  }
}

// ---------------- GEMM 256x256 pipelined (R12, + coalesced mode-0 store) ----
// 8 waves as 4M x 2N (per-wave 64Mx128N; full head span in-thread for rope).
// LDS: 2-slot double buffer of A[256][64]+B[256][64] bf16 panels (128KiB).
// Swizzle: rows are 8 x 16B chunks; LDS[row][ch] = global[row][ch^(row&7)].
// Phase phi (32, BK=64): {kc0 frags | STAGE(phi+1) | kc0 MFMA x32 | kc1 frags
// | kc1 MFMA x32 | vmcnt(0) | raw s_barrier}.
// Block map: XCD chunk of cpx blocks; within chunk M varies fastest.
// mode 0: f32 C row-major (nb=8), stores coalesced via per-wave LDS scratch.
// mode 1: fused QKV (nb=24): Q,K rope'd bf16 [B,H,S,D]; V -> V^T [B,H,D,S].
__global__ __launch_bounds__(512, 2) void gemm256(
    const bf16_t* __restrict__ A, const bf16_t* __restrict__ Bt,
    int nb, int mode, float* __restrict__ Cf,
    bf16_t* __restrict__ outQ, bf16_t* __restrict__ outK,
    bf16_t* __restrict__ outVT,
    const float* __restrict__ cosT, const float* __restrict__ sinT)
{
  __shared__ bf16_t Apan[2][16384];   // [256 rows][64 k] bf16 = 32KB per slot
  __shared__ bf16_t Bpan[2][16384];
  const int bid = blockIdx.x;
  const int cpx = gridDim.x >> 3;
  const int swz = (bid & 7) * cpx + (bid >> 3);   // XCD-chunked (grid%8==0)
  const int RM = cpx / nb;                        // M-rows per chunk
  const int bm = ((swz / cpx) * RM + (swz % RM)) * 256;   // M fastest in chunk
  const int bn = ((swz % cpx) / RM) * 256;
  const int tid = threadIdx.x;
  const int w = tid >> 6, l = tid & 63;
  const int wr = w >> 1, wc = w & 1;              // 4M x 2N
  const int fr = l & 15, g4 = l >> 4;

  const bf16_t* aS[4];
  const bf16_t* bS[4];
  int dst[4];
  #pragma unroll
  for (int i = 0; i < 4; ++i) {
    int c = tid + i * 512;
    int row = c >> 3, ch = c & 7;
    int sc = (ch ^ (row & 7)) * 8;
    aS[i] = A  + (size_t)(bm + row) * 2048 + sc;
    bS[i] = Bt + (size_t)(bn + row) * 2048 + sc;
    dst[i] = c * 16;
  }

  int aOff[2][4], bOff[2][8];
  #pragma unroll
  for (int kc = 0; kc < 2; ++kc) {
    #pragma unroll
    for (int m = 0; m < 4; ++m) {
      int R = wr * 64 + m * 16 + fr;
      aOff[kc][m] = R * 128 + (((kc * 4 + g4) ^ (R & 7)) << 4);
    }
    #pragma unroll
    for (int n = 0; n < 8; ++n) {
      int R = wc * 128 + n * 16 + fr;
      bOff[kc][n] = R * 128 + (((kc * 4 + g4) ^ (R & 7)) << 4);
    }
  }

  f32x4 acc[4][8];
  #pragma unroll
  for (int m = 0; m < 4; ++m)
    #pragma unroll
    for (int n = 0; n < 8; ++n) acc[m][n] = (f32x4){0.f, 0.f, 0.f, 0.f};

  auto STAGE = [&](int t) {        // stage K-tile t (64 wide) into slot t&1
    const int slot = t & 1;
    const int kb = t * 64;
    char* dA = (char*)&Apan[slot][0];
    char* dB = (char*)&Bpan[slot][0];
    #pragma unroll
    for (int i = 0; i < 4; ++i) {
      async_copy16(aS[i] + kb, dA + dst[i]);
      async_copy16(bS[i] + kb, dB + dst[i]);
    }
  };

  STAGE(0);
  __syncthreads();   // prologue: tile 0 landed (full drain, once)

  #pragma unroll 1
  for (int phi = 0; phi < 32; ++phi) {
    const int slot = phi & 1;
    const char* pa = (const char*)&Apan[slot][0];
    const char* pb = (const char*)&Bpan[slot][0];

    bf16x8 af0[4], bf0[8];
    #pragma unroll
    for (int m = 0; m < 4; ++m) af0[m] = *(const bf16x8*)(pa + aOff[0][m]);
    #pragma unroll
    for (int n = 0; n < 8; ++n) bf0[n] = *(const bf16x8*)(pb + bOff[0][n]);
    if (phi < 31) STAGE(phi + 1);
    __builtin_amdgcn_s_setprio(1);
    #pragma unroll
    for (int m = 0; m < 4; ++m)
      #pragma unroll
      for (int n = 0; n < 8; ++n)
        acc[m][n] = mfma16x16x32(af0[m], bf0[n], acc[m][n]);
    __builtin_amdgcn_s_setprio(0);

    bf16x8 af1[4], bf1[8];
    #pragma unroll
    for (int m = 0; m < 4; ++m) af1[m] = *(const bf16x8*)(pa + aOff[1][m]);
    #pragma unroll
    for (int n = 0; n < 8; ++n) bf1[n] = *(const bf16x8*)(pb + bOff[1][n]);
    __builtin_amdgcn_s_setprio(1);
    #pragma unroll
    for (int m = 0; m < 4; ++m)
      #pragma unroll
      for (int n = 0; n < 8; ++n)
        acc[m][n] = mfma16x16x32(af1[m], bf1[n], acc[m][n]);
    __builtin_amdgcn_s_setprio(0);

    asm volatile("s_waitcnt vmcnt(0)" ::: "memory");
    __builtin_amdgcn_sched_barrier(0);
    __builtin_amdgcn_s_barrier();
    __builtin_amdgcn_sched_barrier(0);
  }

  if (mode == 0) {
    // coalesced f32 store: per-wave 16KB LDS scratch (panels dead after loop;
    // last s_barrier of the main loop synchronized all waves).
    float* S = (w < 4) ? (float*)((char*)&Apan[0][0] + w * 16384)
                       : (float*)((char*)&Bpan[0][0] + (w - 4) * 16384);
    #pragma unroll
    for (int h = 0; h < 2; ++h) {           // halves: rows 0..31 / 32..63
      #pragma unroll
      for (int mm = 0; mm < 2; ++mm) {
        int m = h * 2 + mm;
        #pragma unroll
        for (int n = 0; n < 8; ++n)
          #pragma unroll
          for (int j = 0; j < 4; ++j)
            S[(mm * 16 + g4 * 4 + j) * 128 + n * 16 + fr] = acc[m][n][j];
      }
      // rows of 512B, one row per instruction (64 lanes x float2)
      #pragma unroll
      for (int r2 = 0; r2 < 32; ++r2) {
        float2 v = *(const float2*)&S[r2 * 128 + l * 2];
        int row = bm + wr * 64 + h * 32 + r2;
        *(float2*)&Cf[(size_t)row * 2048 + bn + wc * 128 + l * 2] = v;
      }
    }
    return;
  }

  // ---- fused QKV epilogue ----
  const int colbase = bn + wc * 128;          // wave-uniform, multiple of 128
  const int proj = colbase >> 11;             // 0=Q 1=K 2=V
  const int hh = (colbase & 2047) >> 7;
  if (proj == 2) {
    #pragma unroll
    for (int m = 0; m < 4; ++m) {
      int row0 = bm + wr * 64 + m * 16 + g4 * 4;
      int b_ = row0 >> 12, sr = row0 & 4095;
      #pragma unroll
      for (int n = 0; n < 8; ++n) {
        int d_ = n * 16 + fr;
        bf16x4 pkv;
        #pragma unroll
        for (int j = 0; j < 4; ++j) pkv[j] = (bf16_t)acc[m][n][j];
        *(bf16x4*)&outVT[(((size_t)(b_ * 16 + hh)) * 128 + d_) * 4096 + sr] = pkv;
      }
    }
  } else {
    bf16_t* dst_ = proj ? outK : outQ;
    #pragma unroll
    for (int m = 0; m < 4; ++m) {
      int row0 = bm + wr * 64 + m * 16 + g4 * 4;
      int b_ = row0 >> 12, s0 = row0 & 4095;
      size_t hbase = ((size_t)(b_ * 16 + hh)) * 4096;
      #pragma unroll
      for (int n = 0; n < 4; ++n) {
        int d = n * 16 + fr;
        #pragma unroll
        for (int j = 0; j < 4; ++j) {
          int s = s0 + j;
          float c  = cosT[s * 64 + d];
          float sn = sinT[s * 64 + d];
          float x0 = acc[m][n][j], x1 = acc[m][n + 4][j];
          dst_[(hbase + s) * 128 + d]      = (bf16_t)(x0 * c - x1 * sn);
          dst_[(hbase + s) * 128 + d + 64] = (bf16_t)(x1 * c + x0 * sn);
        }
      }
    }
  }
}

// ---------------- sparse flash attention (R9/R12 version: KVBLK=64) ---------
__global__ __launch_bounds__(512, 4) void attn_kernel(
    const bf16_t* __restrict__ Qf, const bf16_t* __restrict__ Kf,
    const bf16_t* __restrict__ Vt, const int* __restrict__ anchors,
    bf16_t* __restrict__ outB)   // [B,S,2048] bf16
{
  __shared__ bf16_t Kl[2][8192];    // [64 tok][128 d] swizzled, 16KB each
  __shared__ bf16_t Vl[2][8192];    // [128 d][64 tok] swizzled, 16KB each
  __shared__ bf16_t Pbuf[8][1024];  // per-wave 2KB  (total LDS = 80KB exact)
  const int orig = blockIdx.x;
  const int blk = (orig & 7) * 128 + (orig >> 3);   // XCD-chunked swizzle
  const int qt = 31 - (blk & 31);                   // long blocks first
  const int h = (blk >> 5) & 15, b = blk >> 9;
  const int bh = b * 16 + h;
  const int tid = threadIdx.x, w = tid >> 6, l = tid & 63;
  const int fr = l & 15, g4 = l >> 4;
  const float scale = 0.08838834764831845f;   // 1/sqrt(128)

  const int* anc = anchors + ((size_t)bh * 32 + qt) * 7;
  unsigned long long pk = 0;
  int nt = 0;
  #pragma unroll
  for (int t = 0; t < 7; ++t) {
    int v = anc[t];
    if (v <= qt) { pk |= (unsigned long long)v << (5 * nt); ++nt; }
  }
  pk |= (unsigned long long)qt << (5 * nt); ++nt;   // local tile last
  const int NS = nt * 2;

  const bf16_t* Qbase = Qf + (size_t)bh * 4096 * 128;
  const bf16_t* Kbase = Kf + (size_t)bh * 4096 * 128;
  const bf16_t* Vbase = Vt + (size_t)bh * 128 * 4096;
  char* P = (char*)&Pbuf[w][0];

  auto STAGE = [&](int tb2, int p) {
    const bf16_t* ksrc = Kbase + (size_t)tb2 * 128;
    const bf16_t* vsrc = Vbase + tb2;
    char* kd = (char*)&Kl[p][0];
    char* vd = (char*)&Vl[p][0];
    #pragma unroll
    for (int i = 0; i < 2; ++i) {
      int c = tid + i * 512;                 // 0..1023
      int kr = c >> 4, kcol = c & 15;        // K: 64 rows x 16 chunks
      async_copy16(ksrc + (size_t)kr * 128 + (size_t)((kcol ^ (kr & 7)) * 8),
                   kd + c * 16);
      int vr = c >> 3, vcol = c & 7;         // V^T: 128 rows x 8 chunks
      async_copy16(vsrc + (size_t)vr * 4096 + (size_t)((vcol ^ (vr & 7)) * 8),
                   vd + c * 16);
    }
  };

  const int qrow = qt * 128 + w * 16 + fr;
  bf16x8 aq[4];
  #pragma unroll
  for (int kc = 0; kc < 4; ++kc)
    aq[kc] = *(const bf16x8*)(Qbase + (size_t)qrow * 128 + kc * 32 + g4 * 8);

  STAGE((int)(pk & 31) * 128, 0);
  __syncthreads();   // step-0 buffers landed

  float mrun = -1e30f, lrun = 0.f;
  f32x4 o[8];
  #pragma unroll
  for (int nd = 0; nd < 8; ++nd) o[nd] = (f32x4){0.f, 0.f, 0.f, 0.f};

  for (int s = 0; s < NS; ++s) {
    const int p = s & 1;
    const int ts = (int)((pk >> (5 * (s >> 1))) & 31);
    const bool domask = (ts == qt);
    if (s + 1 < NS) {
      int s1 = s + 1;
      int ts1 = (int)((pk >> (5 * (s1 >> 1))) & 31);
      STAGE(ts1 * 128 + (s1 & 1) * 64, p ^ 1);
    }

    f32x4 sc[4];
    #pragma unroll
    for (int n = 0; n < 4; ++n) sc[n] = (f32x4){0.f, 0.f, 0.f, 0.f};
    #pragma unroll
    for (int kc = 0; kc < 4; ++kc) {
      bf16x8 kf[4];
      #pragma unroll
      for (int n = 0; n < 4; ++n) {
        int r = n * 16 + fr;
        kf[n] = *(const bf16x8*)((const char*)&Kl[p][0] +
                 r * 256 + (((kc * 4 + g4) ^ (r & 7)) << 4));
      }
      #pragma unroll
      for (int n = 0; n < 4; ++n)
        sc[n] = mfma16x16x32(kf[n], aq[kc], sc[n]);
    }

    float rmax = -1e30f;
    if (domask) {
      const int qr = w * 16 + fr;
      #pragma unroll
      for (int n = 0; n < 4; ++n)
        #pragma unroll
        for (int j = 0; j < 4; ++j) {
          float lg = sc[n][j] * scale;
          int tok = (s & 1) * 64 + n * 16 + g4 * 4 + j;
          if (tok > qr) lg = -1e10f;
          sc[n][j] = lg;
          rmax = fmaxf(rmax, lg);
        }
    } else {
      #pragma unroll
      for (int n = 0; n < 4; ++n)
        #pragma unroll
        for (int j = 0; j < 4; ++j) {
          float lg = sc[n][j] * scale;
          sc[n][j] = lg;
          rmax = fmaxf(rmax, lg);
        }
    }
    rmax = fmaxf(rmax, __shfl_xor(rmax, 16));
    rmax = fmaxf(rmax, __shfl_xor(rmax, 32));
    if (__any(rmax > mrun + 8.f)) {          // defer-max (T13)
      float mnew = fmaxf(mrun, rmax);
      float alpha = __expf(mrun - mnew);
      lrun *= alpha;
      #pragma unroll
      for (int nd = 0; nd < 8; ++nd)
        #pragma unroll
        for (int j = 0; j < 4; ++j) o[nd][j] *= alpha;
      mrun = mnew;
    }
    float rsum = 0.f;
    #pragma unroll
    for (int n = 0; n < 4; ++n) {
      bf16x4 pkv;
      #pragma unroll
      for (int j = 0; j < 4; ++j) {
        float pe = __expf(sc[n][j] - mrun);
        rsum += pe;
        pkv[j] = (bf16_t)pe;
      }
      int off = fr * 128 + ((((n << 1) | (g4 >> 1)) ^ (fr & 7)) << 4) + ((g4 & 1) << 3);
      *(bf16x4*)(P + off) = pkv;
    }
    rsum += __shfl_xor(rsum, 16);
    rsum += __shfl_xor(rsum, 32);
    lrun += rsum;

    #pragma unroll
    for (int kc2 = 0; kc2 < 2; ++kc2) {
      bf16x8 av[8];
      #pragma unroll
      for (int nd = 0; nd < 8; ++nd) {
        int r = nd * 16 + fr;
        av[nd] = *(const bf16x8*)((const char*)&Vl[p][0] +
                  r * 128 + (((kc2 * 4 + g4) ^ (r & 7)) << 4));
      }
      bf16x8 bp = *(const bf16x8*)(P + fr * 128 + ((((kc2 << 2) | g4) ^ (fr & 7)) << 4));
      #pragma unroll
      for (int nd = 0; nd < 8; ++nd)
        o[nd] = mfma16x16x32(av[nd], bp, o[nd]);
    }
    __syncthreads();
  }

  {
    char* E = (char*)&Kl[0][0] + w * 4096;   // 16 rows x 256B per wave
    float inv = 1.0f / lrun;
    #pragma unroll
    for (int nd = 0; nd < 8; ++nd) {
      bf16x4 pkv;
      #pragma unroll
      for (int j = 0; j < 4; ++j) pkv[j] = (bf16_t)(o[nd][j] * inv);
      int off = fr * 256 + ((((nd << 1) | (g4 >> 1)) ^ (fr & 7)) << 4) + ((g4 & 1) << 3);
      *(bf16x4*)(E + off) = pkv;
    }
    #pragma unroll
    for (int i = 0; i < 4; ++i) {
      int r = i * 4 + g4;
      int off = r * 256 + ((fr ^ (r & 7)) << 4);
      bf16x8 vrow = *(const bf16x8*)(E + off);
      size_t gaddr = (((size_t)b * 4096 + qt * 128 + w * 16 + r) * 2048)
                     + h * 128 + fr * 8;
      *(bf16x8*)(outB + gaddr) = vrow;
    }
  }
}

// ---------------------------------------------------------------------------
// workspace layout (bytes)
#define OFF_XB   ((size_t)0)            // x bf16            [8192][2048]  32MB
#define OFF_WCAT ((size_t)33554432)     // concat wq^T|wk^T|wv^T bf16 [6144][2048] 24MB
#define OFF_WOT  ((size_t)58720256)     // wo^T bf16 [2048][2048] 8MB
#define OFF_QF   ((size_t)67108864)     // Q bf16 [B,H,S,D]  32MB
#define OFF_KF   ((size_t)100663296)    // K bf16 [B,H,S,D]  32MB
#define OFF_AT   ((size_t)134217728)    // attn out [B,S,2048] bf16 32MB
#define OFF_VT   ((size_t)167772160)    // V^T bf16 [B,H,D,S] 32MB

extern "C" void kernel_launch(void* const* d_in, const int* in_sizes, int n_in,
                              void* d_out, int out_size, void* d_ws, size_t ws_size,
                              hipStream_t stream) {
  (void)in_sizes; (void)n_in; (void)out_size; (void)ws_size;
  const float* x    = (const float*)d_in[0];
  const float* wq   = (const float*)d_in[1];
  const float* wk   = (const float*)d_in[2];
  const float* wv   = (const float*)d_in[3];
  const float* wo   = (const float*)d_in[4];
  const float* cosT = (const float*)d_in[5];
  const float* sinT = (const float*)d_in[6];
  const int*   anc  = (const int*)d_in[7];
  float* out = (float*)d_out;
  char* ws = (char*)d_ws;

  bf16_t* xb   = (bf16_t*)(ws + OFF_XB);
  bf16_t* wcat = (bf16_t*)(ws + OFF_WCAT);
  bf16_t* wot  = (bf16_t*)(ws + OFF_WOT);
  bf16_t* Qf   = (bf16_t*)(ws + OFF_QF);
  bf16_t* Kf   = (bf16_t*)(ws + OFF_KF);
  bf16_t* Vt   = (bf16_t*)(ws + OFF_VT);
  bf16_t* attnB = (bf16_t*)(ws + OFF_AT);

  // prep: 4096 wtrans blocks + 16384 cvt blocks in one dispatch
  prep_kernel<<<20480, 256, 0, stream>>>(x, wq, wk, wv, wo, xb, wcat, wot);
  // fused QKV projection + RoPE + V^T (grid 768 = 32 M-blocks x 24 N-blocks)
  gemm256<<<768, 512, 0, stream>>>(xb, wcat, 24, 1, nullptr, Qf, Kf, Vt, cosT, sinT);
  attn_kernel<<<1024, 512, 0, stream>>>(Qf, Kf, Vt, anc, attnB);
  // output projection (grid 256 = 32 x 8)
  gemm256<<<256, 512, 0, stream>>>(attnB, wot, 8, 0, out, nullptr, nullptr, nullptr,
                                   nullptr, nullptr);
}

// Round 15
// 351.400 us; speedup vs baseline: 1.0972x; 1.0016x over previous
//
#include <hip/hip_runtime.h>
#include <hip/hip_bf16.h>

// ---------------------------------------------------------------------------
// KascadeReuseAttention: B=2,S=4096,H=16,D=128, TILE=128, T=32, TOPK=7(+local)
// R15: attn -> 48KB LDS (single K + single V + P) with split-stage 3-barrier
// pipeline: stage K(s+1) under softmax+PV, stage V(s+1) under next QK,
// counted vmcnt(2). >=2 blocks/CU guaranteed by LDS. GEMM/prep = R14.
// ---------------------------------------------------------------------------

typedef __bf16 bf16_t;
using bf16x8 = __attribute__((ext_vector_type(8))) __bf16;
using bf16x4 = __attribute__((ext_vector_type(4))) __bf16;
using f32x4  = __attribute__((ext_vector_type(4))) float;

typedef const __attribute__((address_space(1))) void* gas_ptr;
typedef __attribute__((address_space(3))) void* las_ptr;

__device__ __forceinline__ void async_copy16(const void* g, void* l) {
  __builtin_amdgcn_global_load_lds((gas_ptr)g, (las_ptr)l, 16, 0, 0);
}

__device__ __forceinline__ f32x4 mfma16x16x32(bf16x8 a, bf16x8 b, f32x4 c) {
  return __builtin_amdgcn_mfma_f32_16x16x32_bf16(a, b, c, 0, 0, 0);
}

#define SBAR0() __builtin_amdgcn_sched_barrier(0)

// -------- prep: weight transpose x4 + x f32->bf16, one dispatch -------------
__global__ void prep_kernel(const float* __restrict__ x, const float* __restrict__ wq,
                            const float* __restrict__ wk, const float* __restrict__ wv,
                            const float* __restrict__ wo, bf16_t* __restrict__ xb,
                            bf16_t* __restrict__ wcat, bf16_t* __restrict__ wot) {
  __shared__ bf16_t t[64][66];
  const int bidx = blockIdx.x;
  if (bidx >= 4096) {
    int idx = (bidx - 4096) * 256 + threadIdx.x;
    float4 v = ((const float4*)x)[idx];
    bf16x4 r;
    r.x = (bf16_t)v.x; r.y = (bf16_t)v.y; r.z = (bf16_t)v.z; r.w = (bf16_t)v.w;
    ((bf16x4*)xb)[idx] = r;
    return;
  }
  const int z = bidx >> 10, bt = bidx & 1023;
  const float* W = (z == 0) ? wq : (z == 1) ? wk : (z == 2) ? wv : wo;
  bf16_t* Wt = (z == 3) ? wot : (wcat + (size_t)z * 2048 * 2048);
  const int r0 = (bt >> 5) * 64, c0 = (bt & 31) * 64;
  const int tx = threadIdx.x & 63, ty = threadIdx.x >> 6;
  #pragma unroll
  for (int i = 0; i < 16; ++i) {
    int r = ty + 4 * i;
    t[r][tx] = (bf16_t)W[(size_t)(r0 + r) * 2048 + c0 + tx];
  }
  __syncthreads();
  #pragma unroll
  for (int i = 0; i < 16; ++i) {
    int n = ty + 4 * i;
    Wt[(size_t)(c0 + n) * 2048 + r0 + tx] = t[tx][n];
  }
}

// ---------------- GEMM 256x256 pipelined (R14, unchanged) -------------------
__global__ __launch_bounds__(512, 2) void gemm256(
    const bf16_t* __restrict__ A, const bf16_t* __restrict__ Bt,
    int nb, int mode, float* __restrict__ Cf,
    bf16_t* __restrict__ outQ, bf16_t* __restrict__ outK,
    bf16_t* __restrict__ outVT,
    const float* __restrict__ cosT, const float* __restrict__ sinT)
{
  __shared__ bf16_t Apan[2][16384];   // [256 rows][64 k] bf16 = 32KB per slot
  __shared__ bf16_t Bpan[2][16384];
  const int bid = blockIdx.x;
  const int cpx = gridDim.x >> 3;
  const int swz = (bid & 7) * cpx + (bid >> 3);   // XCD-chunked (grid%8==0)
  const int RM = cpx / nb;                        // M-rows per chunk
  const int bm = ((swz / cpx) * RM + (swz % RM)) * 256;   // M fastest in chunk
  const int bn = ((swz % cpx) / RM) * 256;
  const int tid = threadIdx.x;
  const int w = tid >> 6, l = tid & 63;
  const int wr = w >> 1, wc = w & 1;              // 4M x 2N
  const int fr = l & 15, g4 = l >> 4;

  const bf16_t* aS[4];
  const bf16_t* bS[4];
  int dst[4];
  #pragma unroll
  for (int i = 0; i < 4; ++i) {
    int c = tid + i * 512;
    int row = c >> 3, ch = c & 7;
    int sc = (ch ^ (row & 7)) * 8;
    aS[i] = A  + (size_t)(bm + row) * 2048 + sc;
    bS[i] = Bt + (size_t)(bn + row) * 2048 + sc;
    dst[i] = c * 16;
  }

  int aOff[2][4], bOff[2][8];
  #pragma unroll
  for (int kc = 0; kc < 2; ++kc) {
    #pragma unroll
    for (int m = 0; m < 4; ++m) {
      int R = wr * 64 + m * 16 + fr;
      aOff[kc][m] = R * 128 + (((kc * 4 + g4) ^ (R & 7)) << 4);
    }
    #pragma unroll
    for (int n = 0; n < 8; ++n) {
      int R = wc * 128 + n * 16 + fr;
      bOff[kc][n] = R * 128 + (((kc * 4 + g4) ^ (R & 7)) << 4);
    }
  }

  f32x4 acc[4][8];
  #pragma unroll
  for (int m = 0; m < 4; ++m)
    #pragma unroll
    for (int n = 0; n < 8; ++n) acc[m][n] = (f32x4){0.f, 0.f, 0.f, 0.f};

  auto STAGE = [&](int t) {        // stage K-tile t (64 wide) into slot t&1
    const int slot = t & 1;
    const int kb = t * 64;
    char* dA = (char*)&Apan[slot][0];
    char* dB = (char*)&Bpan[slot][0];
    #pragma unroll
    for (int i = 0; i < 4; ++i) {
      async_copy16(aS[i] + kb, dA + dst[i]);
      async_copy16(bS[i] + kb, dB + dst[i]);
    }
  };

  STAGE(0);
  __syncthreads();   // prologue: tile 0 landed (full drain, once)

  #pragma unroll 1
  for (int phi = 0; phi < 32; ++phi) {
    const int slot = phi & 1;
    const char* pa = (const char*)&Apan[slot][0];
    const char* pb = (const char*)&Bpan[slot][0];

    bf16x8 af0[4], bf0[8];
    #pragma unroll
    for (int m = 0; m < 4; ++m) af0[m] = *(const bf16x8*)(pa + aOff[0][m]);
    #pragma unroll
    for (int n = 0; n < 8; ++n) bf0[n] = *(const bf16x8*)(pb + bOff[0][n]);
    if (phi < 31) STAGE(phi + 1);
    __builtin_amdgcn_s_setprio(1);
    #pragma unroll
    for (int m = 0; m < 4; ++m)
      #pragma unroll
      for (int n = 0; n < 8; ++n)
        acc[m][n] = mfma16x16x32(af0[m], bf0[n], acc[m][n]);
    __builtin_amdgcn_s_setprio(0);

    bf16x8 af1[4], bf1[8];
    #pragma unroll
    for (int m = 0; m < 4; ++m) af1[m] = *(const bf16x8*)(pa + aOff[1][m]);
    #pragma unroll
    for (int n = 0; n < 8; ++n) bf1[n] = *(const bf16x8*)(pb + bOff[1][n]);
    __builtin_amdgcn_s_setprio(1);
    #pragma unroll
    for (int m = 0; m < 4; ++m)
      #pragma unroll
      for (int n = 0; n < 8; ++n)
        acc[m][n] = mfma16x16x32(af1[m], bf1[n], acc[m][n]);
    __builtin_amdgcn_s_setprio(0);

    asm volatile("s_waitcnt vmcnt(0)" ::: "memory");
    SBAR0();
    __builtin_amdgcn_s_barrier();
    SBAR0();
  }

  if (mode == 0) {
    // coalesced f32 store via per-wave 16KB LDS scratch (panels dead)
    float* S = (w < 4) ? (float*)((char*)&Apan[0][0] + w * 16384)
                       : (float*)((char*)&Bpan[0][0] + (w - 4) * 16384);
    #pragma unroll
    for (int h = 0; h < 2; ++h) {
      #pragma unroll
      for (int mm = 0; mm < 2; ++mm) {
        int m = h * 2 + mm;
        #pragma unroll
        for (int n = 0; n < 8; ++n)
          #pragma unroll
          for (int j = 0; j < 4; ++j)
            S[(mm * 16 + g4 * 4 + j) * 128 + n * 16 + fr] = acc[m][n][j];
      }
      #pragma unroll
      for (int r2 = 0; r2 < 32; ++r2) {
        float2 v = *(const float2*)&S[r2 * 128 + l * 2];
        int row = bm + wr * 64 + h * 32 + r2;
        *(float2*)&Cf[(size_t)row * 2048 + bn + wc * 128 + l * 2] = v;
      }
    }
    return;
  }

  // ---- fused QKV epilogue ----
  const int colbase = bn + wc * 128;
  const int proj = colbase >> 11;             // 0=Q 1=K 2=V
  const int hh = (colbase & 2047) >> 7;
  if (proj == 2) {
    #pragma unroll
    for (int m = 0; m < 4; ++m) {
      int row0 = bm + wr * 64 + m * 16 + g4 * 4;
      int b_ = row0 >> 12, sr = row0 & 4095;
      #pragma unroll
      for (int n = 0; n < 8; ++n) {
        int d_ = n * 16 + fr;
        bf16x4 pkv;
        #pragma unroll
        for (int j = 0; j < 4; ++j) pkv[j] = (bf16_t)acc[m][n][j];
        *(bf16x4*)&outVT[(((size_t)(b_ * 16 + hh)) * 128 + d_) * 4096 + sr] = pkv;
      }
    }
  } else {
    bf16_t* dst_ = proj ? outK : outQ;
    #pragma unroll
    for (int m = 0; m < 4; ++m) {
      int row0 = bm + wr * 64 + m * 16 + g4 * 4;
      int b_ = row0 >> 12, s0 = row0 & 4095;
      size_t hbase = ((size_t)(b_ * 16 + hh)) * 4096;
      #pragma unroll
      for (int n = 0; n < 4; ++n) {
        int d = n * 16 + fr;
        #pragma unroll
        for (int j = 0; j < 4; ++j) {
          int s = s0 + j;
          float c  = cosT[s * 64 + d];
          float sn = sinT[s * 64 + d];
          float x0 = acc[m][n][j], x1 = acc[m][n + 4][j];
          dst_[(hbase + s) * 128 + d]      = (bf16_t)(x0 * c - x1 * sn);
          dst_[(hbase + s) * 128 + d + 64] = (bf16_t)(x1 * c + x0 * sn);
        }
      }
    }
  }
}

// ---------------- sparse flash attention (48KB, split-stage pipeline) -------
// block = (b,h,qt): 512 threads, 8 waves x 16 q-rows. LDS 48KB:
// Kl [64][128] 16KB | Vl [128][64] 16KB | P 8x2KB. >=2 blocks/CU by LDS.
// Step s: QK(s) | vmcnt(0) [V(s) landed] bar1 [Kl free] | stage K(s+1) |
// softmax+PV(s) | bar2 [Vl free] | stage V(s+1) | vmcnt(2) [K(s+1) landed,
// V(s+1) in flight under next QK] bar3. Per-thread outstanding <=4.
__global__ __launch_bounds__(512, 4) void attn_kernel(
    const bf16_t* __restrict__ Qf, const bf16_t* __restrict__ Kf,
    const bf16_t* __restrict__ Vt, const int* __restrict__ anchors,
    bf16_t* __restrict__ outB)   // [B,S,2048] bf16
{
  __shared__ bf16_t SH[24576];      // 48KB: Kl | Vl | P
  bf16_t* Kl = SH;                  // [64 tok][128 d] swizzled, 16KB
  bf16_t* Vl = SH + 8192;           // [128 d][64 tok] swizzled, 16KB
  bf16_t* Pb = SH + 16384;          // per-wave 2KB x 8
  const int orig = blockIdx.x;
  const int blk = (orig & 7) * 128 + (orig >> 3);   // XCD-chunked swizzle
  const int qt = 31 - (blk & 31);                   // long blocks first
  const int h = (blk >> 5) & 15, b = blk >> 9;
  const int bh = b * 16 + h;
  const int tid = threadIdx.x, w = tid >> 6, l = tid & 63;
  const int fr = l & 15, g4 = l >> 4;
  const float scale = 0.08838834764831845f;   // 1/sqrt(128)

  // ---- packed active-tile list (identical in every thread) ----
  const int* anc = anchors + ((size_t)bh * 32 + qt) * 7;
  unsigned long long pk = 0;
  int nt = 0;
  #pragma unroll
  for (int t = 0; t < 7; ++t) {
    int v = anc[t];
    if (v <= qt) { pk |= (unsigned long long)v << (5 * nt); ++nt; }
  }
  pk |= (unsigned long long)qt << (5 * nt); ++nt;   // local tile last
  const int NS = nt * 2;

  const bf16_t* Qbase = Qf + (size_t)bh * 4096 * 128;
  const bf16_t* Kbase = Kf + (size_t)bh * 4096 * 128;
  const bf16_t* Vbase = Vt + (size_t)bh * 128 * 4096;
  char* P = (char*)(Pb + w * 1024);

  auto STAGE_K = [&](int tb2) {     // 64x128 K half-tile, 2 loads/thread
    const bf16_t* ksrc = Kbase + (size_t)tb2 * 128;
    #pragma unroll
    for (int i = 0; i < 2; ++i) {
      int c = tid + i * 512;
      int kr = c >> 4, kcol = c & 15;
      async_copy16(ksrc + (size_t)kr * 128 + (size_t)((kcol ^ (kr & 7)) * 8),
                   (char*)Kl + c * 16);
    }
  };
  auto STAGE_V = [&](int tb2) {     // 128x64 V^T half-tile, 2 loads/thread
    const bf16_t* vsrc = Vbase + tb2;
    #pragma unroll
    for (int i = 0; i < 2; ++i) {
      int c = tid + i * 512;
      int vr = c >> 3, vcol = c & 7;
      async_copy16(vsrc + (size_t)vr * 4096 + (size_t)((vcol ^ (vr & 7)) * 8),
                   (char*)Vl + c * 16);
    }
  };

  // Q fragments (B-operand: col = q-row, k-chunk g4*8), direct from global
  const int qrow = qt * 128 + w * 16 + fr;
  bf16x8 aq[4];
  #pragma unroll
  for (int kc = 0; kc < 4; ++kc)
    aq[kc] = *(const bf16x8*)(Qbase + (size_t)qrow * 128 + kc * 32 + g4 * 8);

  // prologue: K(0),V(0) staged; vmcnt(2) -> K landed (V verified in-step)
  {
    int tb0 = (int)(pk & 31) * 128;
    STAGE_K(tb0);
    STAGE_V(tb0);
    asm volatile("s_waitcnt vmcnt(2)" ::: "memory");
    SBAR0(); __builtin_amdgcn_s_barrier(); SBAR0();
  }

  float mrun = -1e30f, lrun = 0.f;
  f32x4 o[8];
  #pragma unroll
  for (int nd = 0; nd < 8; ++nd) o[nd] = (f32x4){0.f, 0.f, 0.f, 0.f};

  for (int s = 0; s < NS; ++s) {
    const int ts = (int)((pk >> (5 * (s >> 1))) & 31);
    const bool domask = (ts == qt);
    const bool more = (s + 1 < NS);
    int ntb = 0;
    if (more) {
      int s1 = s + 1;
      ntb = (int)((pk >> (5 * (s1 >> 1))) & 31) * 128 + (s1 & 1) * 64;
    }

    // ---- S^T = K Q^T from Kl: sc[n], rows=tok(g4*4+j), cols=q(fr) ----
    f32x4 sc[4];
    #pragma unroll
    for (int n = 0; n < 4; ++n) sc[n] = (f32x4){0.f, 0.f, 0.f, 0.f};
    #pragma unroll
    for (int kc = 0; kc < 4; ++kc) {
      bf16x8 kf[4];
      #pragma unroll
      for (int n = 0; n < 4; ++n) {
        int r = n * 16 + fr;
        kf[n] = *(const bf16x8*)((const char*)Kl +
                 r * 256 + (((kc * 4 + g4) ^ (r & 7)) << 4));
      }
      #pragma unroll
      for (int n = 0; n < 4; ++n)
        sc[n] = mfma16x16x32(kf[n], aq[kc], sc[n]);
    }

    // V(s) landed (only V loads outstanding); all waves done reading Kl
    asm volatile("s_waitcnt vmcnt(0)" ::: "memory");
    SBAR0(); __builtin_amdgcn_s_barrier(); SBAR0();
    if (more) STAGE_K(ntb);        // flies under softmax + PV

    // ---- mask (local tile only) + online softmax ----
    float rmax = -1e30f;
    if (domask) {
      const int qr = w * 16 + fr;
      #pragma unroll
      for (int n = 0; n < 4; ++n)
        #pragma unroll
        for (int j = 0; j < 4; ++j) {
          float lg = sc[n][j] * scale;
          int tok = (s & 1) * 64 + n * 16 + g4 * 4 + j;
          if (tok > qr) lg = -1e10f;
          sc[n][j] = lg;
          rmax = fmaxf(rmax, lg);
        }
    } else {
      #pragma unroll
      for (int n = 0; n < 4; ++n)
        #pragma unroll
        for (int j = 0; j < 4; ++j) {
          float lg = sc[n][j] * scale;
          sc[n][j] = lg;
          rmax = fmaxf(rmax, lg);
        }
    }
    rmax = fmaxf(rmax, __shfl_xor(rmax, 16));
    rmax = fmaxf(rmax, __shfl_xor(rmax, 32));
    if (__any(rmax > mrun + 8.f)) {          // defer-max (T13)
      float mnew = fmaxf(mrun, rmax);
      float alpha = __expf(mrun - mnew);
      lrun *= alpha;
      #pragma unroll
      for (int nd = 0; nd < 8; ++nd)
        #pragma unroll
        for (int j = 0; j < 4; ++j) o[nd][j] *= alpha;
      mrun = mnew;
    }
    float rsum = 0.f;
    #pragma unroll
    for (int n = 0; n < 4; ++n) {
      bf16x4 pkv;
      #pragma unroll
      for (int j = 0; j < 4; ++j) {
        float pe = __expf(sc[n][j] - mrun);
        rsum += pe;
        pkv[j] = (bf16_t)pe;
      }
      int off = fr * 128 + ((((n << 1) | (g4 >> 1)) ^ (fr & 7)) << 4) + ((g4 & 1) << 3);
      *(bf16x4*)(P + off) = pkv;
    }
    rsum += __shfl_xor(rsum, 16);
    rsum += __shfl_xor(rsum, 32);
    lrun += rsum;

    // ---- O^T += V^T P from Vl + per-wave P ----
    #pragma unroll
    for (int kc2 = 0; kc2 < 2; ++kc2) {
      bf16x8 av[8];
      #pragma unroll
      for (int nd = 0; nd < 8; ++nd) {
        int r = nd * 16 + fr;
        av[nd] = *(const bf16x8*)((const char*)Vl +
                  r * 128 + (((kc2 * 4 + g4) ^ (r & 7)) << 4));
      }
      bf16x8 bp = *(const bf16x8*)(P + fr * 128 + ((((kc2 << 2) | g4) ^ (fr & 7)) << 4));
      #pragma unroll
      for (int nd = 0; nd < 8; ++nd)
        o[nd] = mfma16x16x32(av[nd], bp, o[nd]);
    }

    // all waves done reading Vl -> stage V(s+1); retire K(s+1)
    SBAR0(); __builtin_amdgcn_s_barrier(); SBAR0();
    if (more) {
      STAGE_V(ntb);
      asm volatile("s_waitcnt vmcnt(2)" ::: "memory");   // K(s+1) landed
      SBAR0(); __builtin_amdgcn_s_barrier(); SBAR0();
    }
  }

  // ---- epilogue: normalize; O^T -> per-wave scratch (Kl/Vl dead) ----
  {
    char* E = (char*)SH + w * 4096;          // 8 waves x 4KB over Kl+Vl region
    float inv = 1.0f / lrun;
    #pragma unroll
    for (int nd = 0; nd < 8; ++nd) {
      bf16x4 pkv;
      #pragma unroll
      for (int j = 0; j < 4; ++j) pkv[j] = (bf16_t)(o[nd][j] * inv);
      int off = fr * 256 + ((((nd << 1) | (g4 >> 1)) ^ (fr & 7)) << 4) + ((g4 & 1) << 3);
      *(bf16x4*)(E + off) = pkv;
    }
    #pragma unroll
    for (int i = 0; i < 4; ++i) {
      int r = i * 4 + g4;
      int off = r * 256 + ((fr ^ (r & 7)) << 4);
      bf16x8 vrow = *(const bf16x8*)(E + off);
      size_t gaddr = (((size_t)b * 4096 + qt * 128 + w * 16 + r) * 2048)
                     + h * 128 + fr * 8;
      *(bf16x8*)(outB + gaddr) = vrow;
    }
  }
}

// ---------------------------------------------------------------------------
// workspace layout (bytes)
#define OFF_XB   ((size_t)0)            // x bf16            [8192][2048]  32MB
#define OFF_WCAT ((size_t)33554432)     // concat wq^T|wk^T|wv^T bf16 [6144][2048] 24MB
#define OFF_WOT  ((size_t)58720256)     // wo^T bf16 [2048][2048] 8MB
#define OFF_QF   ((size_t)67108864)     // Q bf16 [B,H,S,D]  32MB
#define OFF_KF   ((size_t)100663296)    // K bf16 [B,H,S,D]  32MB
#define OFF_AT   ((size_t)134217728)    // attn out [B,S,2048] bf16 32MB
#define OFF_VT   ((size_t)167772160)    // V^T bf16 [B,H,D,S] 32MB

extern "C" void kernel_launch(void* const* d_in, const int* in_sizes, int n_in,
                              void* d_out, int out_size, void* d_ws, size_t ws_size,
                              hipStream_t stream) {
  (void)in_sizes; (void)n_in; (void)out_size; (void)ws_size;
  const float* x    = (const float*)d_in[0];
  const float* wq   = (const float*)d_in[1];
  const float* wk   = (const float*)d_in[2];
  const float* wv   = (const float*)d_in[3];
  const float* wo   = (const float*)d_in[4];
  const float* cosT = (const float*)d_in[5];
  const float* sinT = (const float*)d_in[6];
  const int*   anc  = (const int*)d_in[7];
  float* out = (float*)d_out;
  char* ws = (char*)d_ws;

  bf16_t* xb   = (bf16_t*)(ws + OFF_XB);
  bf16_t* wcat = (bf16_t*)(ws + OFF_WCAT);
  bf16_t* wot  = (bf16_t*)(ws + OFF_WOT);
  bf16_t* Qf   = (bf16_t*)(ws + OFF_QF);
  bf16_t* Kf   = (bf16_t*)(ws + OFF_KF);
  bf16_t* Vt   = (bf16_t*)(ws + OFF_VT);
  bf16_t* attnB = (bf16_t*)(ws + OFF_AT);

  prep_kernel<<<20480, 256, 0, stream>>>(x, wq, wk, wv, wo, xb, wcat, wot);
  gemm256<<<768, 512, 0, stream>>>(xb, wcat, 24, 1, nullptr, Qf, Kf, Vt, cosT, sinT);
  attn_kernel<<<1024, 512, 0, stream>>>(Qf, Kf, Vt, anc, attnB);
  gemm256<<<256, 512, 0, stream>>>(attnB, wot, 8, 0, out, nullptr, nullptr, nullptr,
                                   nullptr, nullptr);
}